// Round 3
// baseline (199.317 us; speedup 1.0000x reference)
//
#include <hip/hip_runtime.h>
#include <hip/hip_fp16.h>
#include <cmath>

// Fixed problem shape: x = (8, 3, 1024, 1024) fp32.
#define HH   1024
#define WW   1024
#define HW   (HH * WW)

#define SW    64      // tile width  (output cols per block)
#define TH    128     // tile height (output rows per block)
#define T31R  158     // TH + 30
#define T7R   134     // TH + 6
#define SPX   112     // stage row width in px (64 + 24 left + 24 right halo)
#define SOFF  24      // stage col s  <->  image col x0 - SOFF + s
#define UPR   28      // float4 units per stage row (28*4 = 112)

// ---- compile-time gaussian weights (matches np: exp(-d^2/(2 sigma^2)) / sum) ----
constexpr double cexp(double v) {
    double term = 1.0, sum = 1.0;
    for (int i = 1; i < 64; ++i) { term *= v / (double)i; sum += term; }
    return sum;
}
struct GW { float g31[31]; float g7[7]; };
constexpr GW make_gw() {
    GW r{};
    double t31[31]; double s31 = 0.0;
    for (int i = 0; i < 31; ++i) { double d = (double)(i - 15); t31[i] = cexp(-d * d / 128.0); s31 += t31[i]; }
    for (int i = 0; i < 31; ++i) r.g31[i] = (float)(t31[i] / s31);
    double t7[7]; double s7 = 0.0;
    for (int i = 0; i < 7; ++i) { double d = (double)(i - 3); t7[i] = cexp(-d * d / 4.5); s7 += t7[i]; }
    for (int i = 0; i < 7; ++i) r.g7[i] = (float)(t7[i] / s7);
    return r;
}
__constant__ GW GWC = make_gw();

// ---------------------------------------------------------------------------
// V3 vs V2 (dispatch 76µs, VALUBusy 37%, HBM 35%, occ 33%, VGPR 52):
// V2's register prefetch was DEFEATED by the phase-1 barriers: the compiler
// emits s_waitcnt vmcnt(0) before every s_barrier, draining the prefetch
// (tell: VGPR stayed 52). Fix: make phase 1 barrier-FREE. Each wave now
// stages the same 4 rows it h-blurs into a per-wave private stage buffer
// (stage[wave][4][112]); LDS RAW within a wave needs no s_barrier. t31s/t7s
// writes were already wave-disjoint. One single __syncthreads before
// phase 2. Waves drift through all 10 iterations with depth-1 register
// prefetch that now actually stays in flight.
// LDS = 20224 + 17152 + 3584 = 40960 B exactly -> 4 blocks/CU, grid = 4/CU.
// ---------------------------------------------------------------------------
__global__ __launch_bounds__(256, 4)
void fused_tile(const float* __restrict__ x,
                const float* __restrict__ clar,
                const float* __restrict__ tex,
                float* __restrict__ out) {
    __shared__ __align__(16) __half t31s [T31R][SW];
    __shared__ __align__(16) __half t7s  [T7R][SW];
    __shared__ __align__(16) __half stage[4][4][SPX];   // per-wave private

    // XCD swizzle: all 8 bands of one (img,strip) column on one XCD so the
    // 30-row luma halo overlap between vertical neighbors reuses its L2.
    const int id    = blockIdx.x;
    const int xcd   = id & 7;
    const int k     = id >> 3;             // 0..127
    const int combo = xcd * 16 + (k & 15); // 0..127 = img*16 + strip
    const int band  = k >> 4;              // 0..7
    const int img   = combo >> 4;
    const int strip = combo & 15;

    const int y0 = band * TH;
    const int x0 = strip * SW;
    const int t  = threadIdx.x;
    const int w    = t >> 6;               // wave 0..3
    const int lane = t & 63;

    const float* xb = x   + (size_t)img * 3 * HW;
    float*       ob = out + (size_t)img * 3 * HW;

    // ---- per-wave staging geometry: 4 rows x 28 units = 112 units over 64
    // lanes -> unit0 = lane, unit1 = lane+64 (lanes 0..47 only) ----
    const int r0s = lane / UPR;            // 0..2
    const int c0s = lane - UPR * r0s;
    const int u1  = lane + 64;
    const bool has1 = (u1 < 4 * UPR);      // lane < 48
    const int r1s = u1 / UPR;              // 2..3
    const int c1s = u1 - UPR * r1s;
    const int col0 = x0 - SOFF + 4 * c0s;
    const int col1 = x0 - SOFF + 4 * c1s;
    const bool c0ok = (unsigned)col0 < (unsigned)WW;  // 4-aligned: whole float4 in/out
    const bool c1ok = (unsigned)col1 < (unsigned)WW;

    float4 R0, G0, B0, R1, G1, B1;

    // issue iteration `it`'s global loads into registers (no waits here)
    auto issue = [&](int it) {
        const int gbase = it * 16;
        {
            const int tr = gbase + 4 * w + r0s;
            const int y  = y0 - 15 + tr;
            if (tr < T31R && (unsigned)y < (unsigned)HH && c0ok) {
                const float* xr = xb + (size_t)y * WW + col0;
                R0 = *(const float4*)(xr);
                G0 = *(const float4*)(xr + HW);
                B0 = *(const float4*)(xr + 2 * HW);
            } else {
                R0 = make_float4(0.f, 0.f, 0.f, 0.f); G0 = R0; B0 = R0;
            }
        }
        if (has1) {
            const int tr = gbase + 4 * w + r1s;
            const int y  = y0 - 15 + tr;
            if (tr < T31R && (unsigned)y < (unsigned)HH && c1ok) {
                const float* xr = xb + (size_t)y * WW + col1;
                R1 = *(const float4*)(xr);
                G1 = *(const float4*)(xr + HW);
                B1 = *(const float4*)(xr + 2 * HW);
            } else {
                R1 = make_float4(0.f, 0.f, 0.f, 0.f); G1 = R1; B1 = R1;
            }
        }
    };

    issue(0);   // prologue

    // -------- phase 1: BARRIER-FREE. Wave w produces and consumes stage
    // rows tr = 16*it + 4w + r, and h-blurs rows tr = 16*it + (t>>4) which
    // lie in the same [4w, 4w+3] range. --------
    for (int it = 0; it < 10; ++it) {
        // consume prefetched regs -> fp16 luma into this wave's stage rows
        {
            union { float2 f; __half2 h[2]; } W;
            W.h[0] = __floats2half2_rn(fmaf(0.2126f, R0.x, fmaf(0.7152f, G0.x, 0.0722f * B0.x)),
                                       fmaf(0.2126f, R0.y, fmaf(0.7152f, G0.y, 0.0722f * B0.y)));
            W.h[1] = __floats2half2_rn(fmaf(0.2126f, R0.z, fmaf(0.7152f, G0.z, 0.0722f * B0.z)),
                                       fmaf(0.2126f, R0.w, fmaf(0.7152f, G0.w, 0.0722f * B0.w)));
            *(float2*)&stage[w][r0s][4 * c0s] = W.f;   // 8-byte aligned
            if (has1) {
                union { float2 f; __half2 h[2]; } V;
                V.h[0] = __floats2half2_rn(fmaf(0.2126f, R1.x, fmaf(0.7152f, G1.x, 0.0722f * B1.x)),
                                           fmaf(0.2126f, R1.y, fmaf(0.7152f, G1.y, 0.0722f * B1.y)));
                V.h[1] = __floats2half2_rn(fmaf(0.2126f, R1.z, fmaf(0.7152f, G1.z, 0.0722f * B1.z)),
                                           fmaf(0.2126f, R1.w, fmaf(0.7152f, G1.w, 0.0722f * B1.w)));
                *(float2*)&stage[w][r1s][4 * c1s] = V.f;
            }
        }

        // issue next iteration's loads NOW — no barrier follows, so they
        // stay in flight under the h-blur below.
        if (it + 1 < 10) issue(it + 1);

        // h-blur: thread -> stage row (t>>4)&3 of its own wave, 4 px at 4*(t&15)
        {
            const int lr = (t >> 4) & 3;
            const int c  = t & 15;
            const int tr = it * 16 + (t >> 4);
            if (tr < T31R) {
                float win[36];
                #pragma unroll
                for (int q = 0; q < 9; ++q) {
                    union { float2 f; __half2 h[2]; } U;
                    // win[i] <-> stage col 4c+8+i <-> image col x0+4c-16+i
                    U.f = *(const float2*)&stage[w][lr][4 * c + 8 + 4 * q];  // 8B aligned
                    const float2 a = __half22float2(U.h[0]);
                    const float2 b = __half22float2(U.h[1]);
                    win[4 * q]     = a.x; win[4 * q + 1] = a.y;
                    win[4 * q + 2] = b.x; win[4 * q + 3] = b.y;
                }
                float o[4] = {0.f, 0.f, 0.f, 0.f};
                float p[4] = {0.f, 0.f, 0.f, 0.f};
                #pragma unroll
                for (int s = 0; s < 31; ++s) {
                    const float g = GWC.g31[s];
                    o[0] = fmaf(g, win[1 + s], o[0]);
                    o[1] = fmaf(g, win[2 + s], o[1]);
                    o[2] = fmaf(g, win[3 + s], o[2]);
                    o[3] = fmaf(g, win[4 + s], o[3]);
                }
                #pragma unroll
                for (int s = 0; s < 7; ++s) {
                    const float g = GWC.g7[s];
                    p[0] = fmaf(g, win[13 + s], p[0]);
                    p[1] = fmaf(g, win[14 + s], p[1]);
                    p[2] = fmaf(g, win[15 + s], p[2]);
                    p[3] = fmaf(g, win[16 + s], p[3]);
                }
                union { float2 f; __half2 h[2]; } W;
                W.h[0] = __floats2half2_rn(o[0], o[1]);
                W.h[1] = __floats2half2_rn(o[2], o[3]);
                *(float2*)&t31s[tr][4 * c] = W.f;
                if (tr >= 12 && tr < 12 + T7R) {
                    union { float2 f; __half2 h[2]; } V;
                    V.h[0] = __floats2half2_rn(p[0], p[1]);
                    V.h[1] = __floats2half2_rn(p[2], p[3]);
                    *(float2*)&t7s[tr - 12][4 * c] = V.f;
                }
            }
        }
        // NO __syncthreads here
    }

    __syncthreads();   // the ONLY barrier: t31s/t7s complete before phase 2

    // ---------------- phase 2: vertical blurs + combine, 2 cols/thread ----------------
    const float ca = tanhf(clar[0]) * 0.5f;
    const float ta = tanhf(tex[0]) * 0.3f;

    const int cc = (t & 31) * 2;          // even column within tile
    const int rg = t >> 5;                // row group 0..7
    const int r0 = rg * 16;               // output rows r0..r0+15 (tile-rel)

    float2 w31[31];
    #pragma unroll
    for (int q = 0; q < 30; ++q)
        w31[q] = __half22float2(*(const __half2*)&t31s[r0 + q][cc]);
    float2 w7[7];
    #pragma unroll
    for (int q = 0; q < 6; ++q)
        w7[q] = __half22float2(*(const __half2*)&t7s[r0 + q][cc]);

    // prefetch x row j=0 (L2/L3-hot re-read)
    {
    const float* p0 = xb + (size_t)(y0 + r0) * WW + x0 + cc;
    float2 R  = *(const float2*)(p0);
    float2 G  = *(const float2*)(p0 + HW);
    float2 Bc = *(const float2*)(p0 + 2 * HW);

    #pragma unroll
    for (int j = 0; j < 16; ++j) {
        w31[(30 + j) % 31] = __half22float2(*(const __half2*)&t31s[r0 + 30 + j][cc]);
        w7 [(6 + j) % 7]   = __half22float2(*(const __half2*)&t7s [r0 + 6 + j][cc]);

        // issue next row's x loads before the conv chain (latency cover)
        float2 Rn, Gn, Bn;
        if (j < 15) {
            const float* pn = xb + (size_t)(y0 + r0 + j + 1) * WW + x0 + cc;
            Rn = *(const float2*)(pn);
            Gn = *(const float2*)(pn + HW);
            Bn = *(const float2*)(pn + 2 * HW);
        }

        float2 a31 = make_float2(0.f, 0.f);
        #pragma unroll
        for (int q = 0; q < 31; ++q) {
            const float g = GWC.g31[q];
            const float2 wv = w31[(j + q) % 31];
            a31.x = fmaf(g, wv.x, a31.x);
            a31.y = fmaf(g, wv.y, a31.y);
        }
        float2 a7 = make_float2(0.f, 0.f);
        #pragma unroll
        for (int q = 0; q < 7; ++q) {
            const float g = GWC.g7[q];
            const float2 wv = w7[(j + q) % 7];
            a7.x = fmaf(g, wv.x, a7.x);
            a7.y = fmaf(g, wv.y, a7.y);
        }

        const int y = y0 + r0 + j;
        float* qo = ob + (size_t)y * WW + x0 + cc;

        const float Lx = fmaf(0.2126f, R.x, fmaf(0.7152f, G.x, 0.0722f * Bc.x));
        const float Ly = fmaf(0.2126f, R.y, fmaf(0.7152f, G.y, 0.0722f * Bc.y));
        const float lex = Lx + ca * (Lx - a31.x) + ta * (Lx - a7.x);
        const float ley = Ly + ca * (Ly - a31.y) + ta * (Ly - a7.y);
        // v_rcp_f32 approx: rel err ~1ulp, far below the 3.9e-3 tolerance
        const float rx = (lex + 1e-6f) * __builtin_amdgcn_rcpf(Lx + 1e-6f);
        const float ry = (ley + 1e-6f) * __builtin_amdgcn_rcpf(Ly + 1e-6f);

        float2 o0, o1, o2;
        o0.x = fminf(fmaxf(R.x  * rx, 0.f), 1.f);  o0.y = fminf(fmaxf(R.y  * ry, 0.f), 1.f);
        o1.x = fminf(fmaxf(G.x  * rx, 0.f), 1.f);  o1.y = fminf(fmaxf(G.y  * ry, 0.f), 1.f);
        o2.x = fminf(fmaxf(Bc.x * rx, 0.f), 1.f);  o2.y = fminf(fmaxf(Bc.y * ry, 0.f), 1.f);
        *(float2*)(qo)          = o0;
        *(float2*)(qo + HW)     = o1;
        *(float2*)(qo + 2 * HW) = o2;

        if (j < 15) { R = Rn; G = Gn; Bc = Bn; }
    }
    }
}

extern "C" void kernel_launch(void* const* d_in, const int* in_sizes, int n_in,
                              void* d_out, int out_size, void* d_ws, size_t ws_size,
                              hipStream_t stream) {
    const float* x    = (const float*)d_in[0];
    const float* clar = (const float*)d_in[1];
    const float* tex  = (const float*)d_in[2];
    float* out = (float*)d_out;

    dim3 grid(8 * 16 * 8);   // 1024 blocks: 8 imgs x 16 strips x 8 bands = 4/CU exact
    dim3 block(256);
    hipLaunchKernelGGL(fused_tile, grid, block, 0, stream, x, clar, tex, out);
}